// Round 4
// baseline (103.239 us; speedup 1.0000x reference)
//
#include <hip/hip_runtime.h>

#define BB 2048
#define DD 4096
#define PP 64
#define KK 64
#define EE 8
#define C2 128
#define NBLK (BB / 4)

typedef __attribute__((ext_vector_type(8))) short short8;
typedef __attribute__((ext_vector_type(4))) float floatx4;

__device__ inline unsigned pack2_trunc(float lo, float hi) { // 2 bf16 (truncate) in 1 u32
    unsigned ul = __builtin_bit_cast(unsigned, lo);
    unsigned uh = __builtin_bit_cast(unsigned, hi);
    return (uh & 0xFFFF0000u) | (ul >> 16);
}

// Single fused kernel: one wave per row (4 rows/block, 512 blocks).
//  - x loaded directly in MFMA A-layout; fp32 col-sum partials for router; trunc->bf16 A-frags
//  - router: 8 dots via 6-step shfl_xor butterflies, strict first-max argmax (np semantics)
//  - selected expert's fp32 weights loaded from global (L2-resident), inline trunc->bf16 B-frags
//  - mfma 16x16x32 bf16, fused (z+bias)^3 epilogue -> 2 logits -> softmax
//  - loss: per-block reduce -> banked global atomics -> last block finalizes
// acc layout (d_ws, zeroed by memset node): acc[0..127] = 8 banks x {sp[8], sc[8]}, acc[128] = counter
__global__ __launch_bounds__(256) void moe_all(
    const float* __restrict__ x, const float* __restrict__ rw,
    const float* __restrict__ ew, const float* __restrict__ eb,
    float* __restrict__ out, float* __restrict__ acc)
{
    __shared__ float wred[4][8];
    __shared__ int   wred_i[4];
    __shared__ unsigned lastv;
    __shared__ float fin[128];

    const int tid  = threadIdx.x;
    const int lane = tid & 63;
    const int w    = tid >> 6;
    const int b    = blockIdx.x * 4 + w;           // one row per wave
    const int r = lane & 15, q = lane >> 4;
    const float* xb = x + (size_t)b * DD;

    // ---- load x in MFMA A-layout; fp32 col-sum partials; pack bf16 A-frags
    float ps[16];
    #pragma unroll
    for (int j = 0; j < 16; ++j) ps[j] = 0.f;
    short8 af[8];                                   // [mt*2+kb]
    #pragma unroll
    for (int mt = 0; mt < 4; ++mt) {
        #pragma unroll
        for (int kb = 0; kb < 2; ++kb) {
            const float* base = xb + (mt * 16 + r) * 64 + kb * 32 + q * 8;
            float4 v0 = *(const float4*)base;
            float4 v1 = *(const float4*)(base + 4);
            ps[kb*8+0] += v0.x; ps[kb*8+1] += v0.y; ps[kb*8+2] += v0.z; ps[kb*8+3] += v0.w;
            ps[kb*8+4] += v1.x; ps[kb*8+5] += v1.y; ps[kb*8+6] += v1.z; ps[kb*8+7] += v1.w;
            uint4 u;
            u.x = pack2_trunc(v0.x, v0.y); u.y = pack2_trunc(v0.z, v0.w);
            u.z = pack2_trunc(v1.x, v1.y); u.w = pack2_trunc(v1.z, v1.w);
            af[mt * 2 + kb] = __builtin_bit_cast(short8, u);
        }
    }

    // ---- router (fp32; strict first-max argmax matches np)
    float d[8];
    #pragma unroll
    for (int e2 = 0; e2 < 8; ++e2) {
        const float* rwe = rw + e2 * KK;
        float4 a0 = *(const float4*)(rwe + q * 8);
        float4 a1 = *(const float4*)(rwe + q * 8 + 4);
        float4 b0 = *(const float4*)(rwe + 32 + q * 8);
        float4 b1 = *(const float4*)(rwe + 32 + q * 8 + 4);
        float t = ps[0]*a0.x + ps[1]*a0.y + ps[2]*a0.z + ps[3]*a0.w
                + ps[4]*a1.x + ps[5]*a1.y + ps[6]*a1.z + ps[7]*a1.w
                + ps[8]*b0.x + ps[9]*b0.y + ps[10]*b0.z + ps[11]*b0.w
                + ps[12]*b1.x + ps[13]*b1.y + ps[14]*b1.z + ps[15]*b1.w;
        t += __shfl_xor(t, 1);  t += __shfl_xor(t, 2);  t += __shfl_xor(t, 4);
        t += __shfl_xor(t, 8);  t += __shfl_xor(t, 16); t += __shfl_xor(t, 32);
        d[e2] = t;
    }
    float gate = d[0]; int e = 0;
    #pragma unroll
    for (int e2 = 1; e2 < 8; ++e2)
        if (d[e2] > gate) { gate = d[e2]; e = e2; }

    if (lane == 0) {
        float on = (gate != 0.f) ? 1.f : 0.f;
        float4 o0 = make_float4(e==0?on:0.f, e==1?on:0.f, e==2?on:0.f, e==3?on:0.f);
        float4 o1 = make_float4(e==4?on:0.f, e==5?on:0.f, e==6?on:0.f, e==7?on:0.f);
        *(float4*)(out + BB * 2 + b * 8)     = o0;   // select0
        *(float4*)(out + BB * 2 + b * 8 + 4) = o1;
    }

    // ---- expert compute: inline fp32->bf16 B-frags, mfma, fused (z+bias)^3
    const float* we = ew + (size_t)e * (C2 * KK);
    float h0 = 0.f, h1 = 0.f;
    #pragma unroll
    for (int nt = 0; nt < 8; ++nt) {
        float bs = eb[e * C2 + nt * 16 + r];         // c = nt*16 + (lane&15)
        const float* wr = we + (nt * 16 + r) * KK + q * 8;
        float4 w0 = *(const float4*)wr;
        float4 w1 = *(const float4*)(wr + 4);
        float4 w2 = *(const float4*)(wr + 32);
        float4 w3 = *(const float4*)(wr + 36);
        uint4 u0, u1;
        u0.x = pack2_trunc(w0.x, w0.y); u0.y = pack2_trunc(w0.z, w0.w);
        u0.z = pack2_trunc(w1.x, w1.y); u0.w = pack2_trunc(w1.z, w1.w);
        u1.x = pack2_trunc(w2.x, w2.y); u1.y = pack2_trunc(w2.z, w2.w);
        u1.z = pack2_trunc(w3.x, w3.y); u1.w = pack2_trunc(w3.z, w3.w);
        short8 bf0 = __builtin_bit_cast(short8, u0);
        short8 bf1 = __builtin_bit_cast(short8, u1);
        #pragma unroll
        for (int mt = 0; mt < 4; ++mt) {
            floatx4 a4 = (floatx4){0.f, 0.f, 0.f, 0.f};
            a4 = __builtin_amdgcn_mfma_f32_16x16x32_bf16(af[mt*2+0], bf0, a4, 0, 0, 0);
            a4 = __builtin_amdgcn_mfma_f32_16x16x32_bf16(af[mt*2+1], bf1, a4, 0, 0, 0);
            float hh = 0.f;
            #pragma unroll
            for (int i = 0; i < 4; ++i) {
                float z = a4[i] + bs;
                hh = fmaf(z * z, z, hh);
            }
            if (nt < 4) h0 += hh; else h1 += hh;
        }
    }
    #pragma unroll
    for (int off = 1; off < 64; off <<= 1) {
        h0 += __shfl_xor(h0, off);
        h1 += __shfl_xor(h1, off);
    }
    if (lane == 0) {
        float l0 = gate * h0, l1 = gate * h1;
        float m = fmaxf(l0, l1);
        float e0 = __expf(l0 - m), e1 = __expf(l1 - m);
        float inv = 1.f / (e0 + e1);
        float2 o; o.x = e0 * inv; o.y = e1 * inv;
        *(float2*)(out + b * 2) = o;
    }

    // ---- loss: block reduce -> banked atomics -> last-block finalize
    if (lane == 0) {
        #pragma unroll
        for (int j = 0; j < 8; ++j) wred[w][j] = d[j];
        wred_i[w] = e;
    }
    __syncthreads();
    if (tid < 16) {
        float v;
        if (tid < 8) {
            v = wred[0][tid] + wred[1][tid] + wred[2][tid] + wred[3][tid];        // sp
        } else {
            int ee = tid - 8;
            v = (float)((wred_i[0]==ee) + (wred_i[1]==ee) + (wred_i[2]==ee) + (wred_i[3]==ee)); // sc
        }
        atomicAdd(&acc[(blockIdx.x & 7) * 16 + tid], v);
    }
    __syncthreads();                                  // barrier drains vmcnt: atomics complete
    if (tid == 0) {
        __threadfence();
        lastv = atomicAdd((unsigned*)(acc + 128), 1u);
    }
    __syncthreads();
    if (lastv == (unsigned)(NBLK - 1)) {              // uniform branch (lastv in LDS)
        if (tid < 128) fin[tid] = atomicAdd(&acc[tid], 0.f);   // coherent reads
        __syncthreads();
        if (tid == 0) {
            float loss = 0.f;
            #pragma unroll
            for (int e2 = 0; e2 < 8; ++e2) {
                float sp = 0.f, sc = 0.f;
                #pragma unroll
                for (int bk = 0; bk < 8; ++bk) {
                    sp += fin[bk * 16 + e2];
                    sc += fin[bk * 16 + 8 + e2];
                }
                loss += (sp / (float)BB) * (sc / (float)BB);
            }
            out[BB * 2 + BB * 8] = loss * (float)EE;
        }
    }
}

extern "C" void kernel_launch(void* const* d_in, const int* in_sizes, int n_in,
                              void* d_out, int out_size, void* d_ws, size_t ws_size,
                              hipStream_t stream) {
    (void)in_sizes; (void)n_in; (void)out_size; (void)ws_size;
    const float* x  = (const float*)d_in[0];
    const float* rw = (const float*)d_in[1];
    const float* ew = (const float*)d_in[2];
    const float* eb = (const float*)d_in[3];
    float* out = (float*)d_out;
    float* acc = (float*)d_ws;                        // 129 floats: 8x16 accumulators + counter

    hipMemsetAsync(acc, 0, 129 * sizeof(float), stream);   // graph-capturable memset node
    moe_all<<<NBLK, 256, 0, stream>>>(x, rw, ew, eb, out, acc);
}

// Round 5
// 92.072 us; speedup vs baseline: 1.1213x; 1.1213x over previous
//
#include <hip/hip_runtime.h>

#define BB 2048
#define DD 4096
#define PP 64
#define KK 64
#define EE 8
#define C2 128
#define NBLK (BB / 4)

typedef __attribute__((ext_vector_type(8))) short short8;
typedef __attribute__((ext_vector_type(4))) float floatx4;

__device__ inline unsigned pack2_trunc(float lo, float hi) { // 2 bf16 (truncate) in 1 u32
    unsigned ul = __builtin_bit_cast(unsigned, lo);
    unsigned uh = __builtin_bit_cast(unsigned, hi);
    return (uh & 0xFFFF0000u) | (ul >> 16);
}

// Fused main kernel: one wave per row (4 rows/block, 512 blocks). No LDS, no barriers.
//  - x loaded directly in MFMA A-layout; fp32 col-sum partials for router; trunc->bf16 A-frags
//  - router: 8 dots via 6-step shfl_xor butterflies, strict first-max argmax (np semantics)
//  - selected expert's fp32 weights loaded from global (L2-resident), inline trunc->bf16 B-frags
//  - mfma 16x16x32 bf16, fused (z+bias)^3 epilogue -> 2 logits -> softmax
//  - select row staged to ws_sel (plain stores) for the tiny loss kernel
__global__ __launch_bounds__(256) void moe_all(
    const float* __restrict__ x, const float* __restrict__ rw,
    const float* __restrict__ ew, const float* __restrict__ eb,
    float* __restrict__ out, float* __restrict__ ws_sel)
{
    const int lane = threadIdx.x & 63;
    const int b = blockIdx.x * 4 + (threadIdx.x >> 6);   // one row per wave
    const int r = lane & 15, q = lane >> 4;
    const float* xb = x + (size_t)b * DD;

    // ---- load x in MFMA A-layout; fp32 col-sum partials; pack bf16 A-frags
    float ps[16];
    #pragma unroll
    for (int j = 0; j < 16; ++j) ps[j] = 0.f;
    short8 af[8];                                        // [mt*2+kb]
    #pragma unroll
    for (int mt = 0; mt < 4; ++mt) {
        #pragma unroll
        for (int kb = 0; kb < 2; ++kb) {
            const float* base = xb + (mt * 16 + r) * 64 + kb * 32 + q * 8;
            float4 v0 = *(const float4*)base;
            float4 v1 = *(const float4*)(base + 4);
            ps[kb*8+0] += v0.x; ps[kb*8+1] += v0.y; ps[kb*8+2] += v0.z; ps[kb*8+3] += v0.w;
            ps[kb*8+4] += v1.x; ps[kb*8+5] += v1.y; ps[kb*8+6] += v1.z; ps[kb*8+7] += v1.w;
            uint4 u;
            u.x = pack2_trunc(v0.x, v0.y); u.y = pack2_trunc(v0.z, v0.w);
            u.z = pack2_trunc(v1.x, v1.y); u.w = pack2_trunc(v1.z, v1.w);
            af[mt * 2 + kb] = __builtin_bit_cast(short8, u);
        }
    }

    // ---- router (fp32; strict first-max argmax matches np)
    float d[8];
    #pragma unroll
    for (int e2 = 0; e2 < 8; ++e2) {
        const float* rwe = rw + e2 * KK;
        float4 a0 = *(const float4*)(rwe + q * 8);
        float4 a1 = *(const float4*)(rwe + q * 8 + 4);
        float4 b0 = *(const float4*)(rwe + 32 + q * 8);
        float4 b1 = *(const float4*)(rwe + 32 + q * 8 + 4);
        float t = ps[0]*a0.x + ps[1]*a0.y + ps[2]*a0.z + ps[3]*a0.w
                + ps[4]*a1.x + ps[5]*a1.y + ps[6]*a1.z + ps[7]*a1.w
                + ps[8]*b0.x + ps[9]*b0.y + ps[10]*b0.z + ps[11]*b0.w
                + ps[12]*b1.x + ps[13]*b1.y + ps[14]*b1.z + ps[15]*b1.w;
        t += __shfl_xor(t, 1);  t += __shfl_xor(t, 2);  t += __shfl_xor(t, 4);
        t += __shfl_xor(t, 8);  t += __shfl_xor(t, 16); t += __shfl_xor(t, 32);
        d[e2] = t;                                       // all lanes hold it
    }
    float gate = d[0]; int e = 0;
    #pragma unroll
    for (int e2 = 1; e2 < 8; ++e2)
        if (d[e2] > gate) { gate = d[e2]; e = e2; }

    if (lane == 0) {
        float4 s0 = make_float4(d[0], d[1], d[2], d[3]);
        float4 s1 = make_float4(d[4], d[5], d[6], d[7]);
        *(float4*)(ws_sel + b * 8)     = s0;             // staged for loss kernel
        *(float4*)(ws_sel + b * 8 + 4) = s1;
        float on = (gate != 0.f) ? 1.f : 0.f;
        float4 o0 = make_float4(e==0?on:0.f, e==1?on:0.f, e==2?on:0.f, e==3?on:0.f);
        float4 o1 = make_float4(e==4?on:0.f, e==5?on:0.f, e==6?on:0.f, e==7?on:0.f);
        *(float4*)(out + BB * 2 + b * 8)     = o0;       // select0
        *(float4*)(out + BB * 2 + b * 8 + 4) = o1;
    }

    // ---- expert compute: inline fp32->bf16 B-frags, mfma, fused (z+bias)^3
    const float* we = ew + (size_t)e * (C2 * KK);
    float h0 = 0.f, h1 = 0.f;
    #pragma unroll
    for (int nt = 0; nt < 8; ++nt) {
        float bs = eb[e * C2 + nt * 16 + r];             // c = nt*16 + (lane&15)
        const float* wr = we + (nt * 16 + r) * KK + q * 8;
        float4 w0 = *(const float4*)wr;
        float4 w1 = *(const float4*)(wr + 4);
        float4 w2 = *(const float4*)(wr + 32);
        float4 w3 = *(const float4*)(wr + 36);
        uint4 u0, u1;
        u0.x = pack2_trunc(w0.x, w0.y); u0.y = pack2_trunc(w0.z, w0.w);
        u0.z = pack2_trunc(w1.x, w1.y); u0.w = pack2_trunc(w1.z, w1.w);
        u1.x = pack2_trunc(w2.x, w2.y); u1.y = pack2_trunc(w2.z, w2.w);
        u1.z = pack2_trunc(w3.x, w3.y); u1.w = pack2_trunc(w3.z, w3.w);
        short8 bf0 = __builtin_bit_cast(short8, u0);
        short8 bf1 = __builtin_bit_cast(short8, u1);
        #pragma unroll
        for (int mt = 0; mt < 4; ++mt) {
            floatx4 a4 = (floatx4){0.f, 0.f, 0.f, 0.f};
            a4 = __builtin_amdgcn_mfma_f32_16x16x32_bf16(af[mt*2+0], bf0, a4, 0, 0, 0);
            a4 = __builtin_amdgcn_mfma_f32_16x16x32_bf16(af[mt*2+1], bf1, a4, 0, 0, 0);
            float hh = 0.f;
            #pragma unroll
            for (int i = 0; i < 4; ++i) {
                float z = a4[i] + bs;
                hh = fmaf(z * z, z, hh);
            }
            if (nt < 4) h0 += hh; else h1 += hh;
        }
    }
    #pragma unroll
    for (int off = 1; off < 64; off <<= 1) {
        h0 += __shfl_xor(h0, off);
        h1 += __shfl_xor(h1, off);
    }
    if (lane == 0) {
        float l0 = gate * h0, l1 = gate * h1;
        float m = fmaxf(l0, l1);
        float e0 = __expf(l0 - m), e1 = __expf(l1 - m);
        float inv = 1.f / (e0 + e1);
        float2 o; o.x = e0 * inv; o.y = e1 * inv;
        *(float2*)(out + b * 2) = o;
    }
}

// loss = E * sum_e (mean_b select[b,e]) * (count_b(argmax==e)/B) — shuffle reduce, no atomics
__global__ __launch_bounds__(256) void loss_kernel(
    const float* __restrict__ ws_sel, float* __restrict__ out)
{
    __shared__ float red[4][16];
    const int t = threadIdx.x;
    const int w = t >> 6, lane = t & 63;

    float p[8] = {0,0,0,0,0,0,0,0};
    float c[8] = {0,0,0,0,0,0,0,0};
    #pragma unroll
    for (int it = 0; it < BB / 256; ++it) {
        int b = it * 256 + t;
        const float4* row = (const float4*)(ws_sel + b * 8);
        float4 r0 = row[0], r1 = row[1];
        float v[8] = {r0.x, r0.y, r0.z, r0.w, r1.x, r1.y, r1.z, r1.w};
        float g = v[0]; int ix = 0;
        #pragma unroll
        for (int e2 = 1; e2 < 8; ++e2)
            if (v[e2] > g) { g = v[e2]; ix = e2; }       // strict >: first-max
        #pragma unroll
        for (int e2 = 0; e2 < 8; ++e2) p[e2] += v[e2];
        c[ix] += 1.f;
    }
    #pragma unroll
    for (int off = 32; off > 0; off >>= 1) {
        #pragma unroll
        for (int e2 = 0; e2 < 8; ++e2) {
            p[e2] += __shfl_xor(p[e2], off);
            c[e2] += __shfl_xor(c[e2], off);
        }
    }
    if (lane == 0) {
        #pragma unroll
        for (int e2 = 0; e2 < 8; ++e2) { red[w][e2] = p[e2]; red[w][8 + e2] = c[e2]; }
    }
    __syncthreads();
    if (t == 0) {
        float loss = 0.f;
        #pragma unroll
        for (int e2 = 0; e2 < 8; ++e2) {
            float sp = red[0][e2] + red[1][e2] + red[2][e2] + red[3][e2];
            float sc = red[0][8 + e2] + red[1][8 + e2] + red[2][8 + e2] + red[3][8 + e2];
            loss += (sp / (float)BB) * (sc / (float)BB);
        }
        out[BB * 2 + BB * 8] = loss * (float)EE;
    }
}

extern "C" void kernel_launch(void* const* d_in, const int* in_sizes, int n_in,
                              void* d_out, int out_size, void* d_ws, size_t ws_size,
                              hipStream_t stream) {
    (void)in_sizes; (void)n_in; (void)out_size; (void)ws_size;
    const float* x  = (const float*)d_in[0];
    const float* rw = (const float*)d_in[1];
    const float* ew = (const float*)d_in[2];
    const float* eb = (const float*)d_in[3];
    float* out = (float*)d_out;
    float* ws_sel = (float*)d_ws;                        // 64 KB: per-row selects

    moe_all<<<NBLK, 256, 0, stream>>>(x, rw, ew, eb, out, ws_sel);
    loss_kernel<<<1, 256, 0, stream>>>(ws_sel, out);
}